// Round 1
// baseline (568.728 us; speedup 1.0000x reference)
//
#include <hip/hip_runtime.h>
#include <hip/hip_bf16.h>
#include <stdint.h>

// Problem constants
//   feats   [8,1024,32,32] fp32   -> rows i = b*1024 + (h*32+w), NI=8192
//   conv_w  [256,1024] fp32
//   conv_b  [256] fp32
//   codebook[16384,256] fp32
// Outputs: z_q [8,256,32,32] fp32 (2097152) + loss scalar (1)

typedef float f32x4 __attribute__((ext_vector_type(4)));
typedef short s16x8 __attribute__((ext_vector_type(8)));

__device__ __forceinline__ void gl2lds16(const void* g, void* l) {
  __builtin_amdgcn_global_load_lds(
      (const __attribute__((address_space(1))) void*)g,
      (__attribute__((address_space(3))) void*)l, 16, 0, 0);
}

// fp32 -> bf16 RNE via bit trick (no NaN inputs here)
__device__ __forceinline__ unsigned short f2bf(float f) {
  unsigned u = __float_as_uint(f);
  u = u + 0x7FFFu + ((u >> 16) & 1u);
  return (unsigned short)(u >> 16);
}
__device__ __forceinline__ float bf2f(unsigned short u) {
  return __uint_as_float(((unsigned)u) << 16);
}

__device__ __forceinline__ unsigned long long shfl_xor_u64(unsigned long long v, int m) {
  int lo = __shfl_xor((int)(unsigned)(v & 0xFFFFFFFFull), m, 64);
  int hi = __shfl_xor((int)(unsigned)(v >> 32), m, 64);
  return (((unsigned long long)(unsigned)hi) << 32) | (unsigned)lo;
}

__global__ void k_init(float* lossw) {
  if (threadIdx.x == 0) lossw[0] = 0.0f;
}

// codebook fp32 [16384][256] -> cb2 bf16 [16384][512] = [hi|lo], ce[j]=||e_j||^2 fp32
__global__ void k_prep_cb(const float* __restrict__ cbk,
                          unsigned short* __restrict__ cb2,
                          float* __restrict__ ce) {
  int j = blockIdx.x, t = threadIdx.x;
  float v = cbk[(size_t)j * 256 + t];
  unsigned short hi = f2bf(v);
  cb2[(size_t)j * 512 + t] = hi;
  cb2[(size_t)j * 512 + 256 + t] = f2bf(v - bf2f(hi));
  float s = v * v;
  #pragma unroll
  for (int m = 32; m; m >>= 1) s += __shfl_down(s, m, 64);
  __shared__ float ps[4];
  if ((t & 63) == 0) ps[t >> 6] = s;
  __syncthreads();
  if (t == 0) ce[j] = ps[0] + ps[1] + ps[2] + ps[3];
}

// conv_w [256][1024] -> W2 bf16 [256][2048] = [hi|lo]
__global__ void k_prep_w(const float* __restrict__ Wsrc, unsigned short* __restrict__ W2) {
  int e = blockIdx.x, t = threadIdx.x;
  #pragma unroll
  for (int k = 0; k < 4; ++k) {
    int c = t + k * 256;
    float v = Wsrc[(size_t)e * 1024 + c];
    unsigned short hi = f2bf(v);
    W2[(size_t)e * 2048 + c] = hi;
    W2[(size_t)e * 2048 + 1024 + c] = f2bf(v - bf2f(hi));
  }
}

// feats [8][1024 c][1024 s] -> featsT bf16 [8192 i][2048] = [hi(c)|lo(c)], i=b*1024+s
__global__ void k_tr_feats(const float* __restrict__ feats, unsigned short* __restrict__ At) {
  __shared__ float tile[32][33];
  int b = blockIdx.z, c0 = blockIdx.x * 32, s0 = blockIdx.y * 32;
  int t = threadIdx.x;
  int tc = t >> 5, ts = t & 31;
  #pragma unroll
  for (int k = 0; k < 4; ++k)
    tile[tc + k * 8][ts] = feats[((size_t)b * 1024 + c0 + tc + k * 8) * 1024 + s0 + ts];
  __syncthreads();
  #pragma unroll
  for (int k = 0; k < 4; ++k) {
    int sr = tc + k * 8, cw = ts;
    float v = tile[cw][sr];
    size_t row = (size_t)(b * 1024 + s0 + sr) * 2048;
    unsigned short hi = f2bf(v);
    At[row + c0 + cw] = hi;
    At[row + 1024 + c0 + cw] = f2bf(v - bf2f(hi));
  }
}

// GEMM1: zf[i][e] = sum_c feats[i][c]*W[e][c] + b[e], split-precision (logical K=3072)
// A = featsT [8192][2048] segments map: seg{0,1,2} -> {hi, hi, lo}
// B = W2     [256][2048]  segments map: seg{0,1,2} -> {hi, lo, hi}
// BM=BN=64, 4 waves 2x2 (wave 32x32), grid (4,128)
__global__ __launch_bounds__(256, 2)
void k_gemm1(const unsigned short* __restrict__ At, const unsigned short* __restrict__ Bw,
             const float* __restrict__ bias, float* __restrict__ zf,
             unsigned short* __restrict__ zb) {
  __shared__ __align__(16) uint8_t lds[1024 * 16];  // A 8KB @0, B 8KB @8192
  uint8_t* ldsA = lds;
  uint8_t* ldsB = lds + 512 * 16;
  const int t = threadIdx.x, w = t >> 6, l = t & 63;
  const int wy = w >> 1, wx = w & 1, l15 = l & 15, q = l >> 4;
  const int ib = blockIdx.y * 64, eb = blockIdx.x * 64;
  f32x4 acc[2][2] = {};
  for (int kt = 0; kt < 48; ++kt) {
    int seg = kt >> 4, c0 = (kt & 15) * 64;
    int kA = (seg == 2 ? 1024 : 0) + c0;
    int kB = (seg == 1 ? 1024 : 0) + c0;
    __syncthreads();
    #pragma unroll
    for (int r = 0; r < 2; ++r) {
      int P = t + 256 * r;  // packet: kp = P>>6, m = P&63; LDS layout [kp][m]
      gl2lds16(At + (size_t)(ib + (P & 63)) * 2048 + kA + (P >> 6) * 8, ldsA + P * 16);
    }
    #pragma unroll
    for (int r = 0; r < 2; ++r) {
      int P = t + 256 * r;
      gl2lds16(Bw + (size_t)(eb + (P & 63)) * 2048 + kB + (P >> 6) * 8, ldsB + P * 16);
    }
    __syncthreads();
    #pragma unroll
    for (int s = 0; s < 2; ++s) {
      s16x8 a[2], b[2];
      #pragma unroll
      for (int fr = 0; fr < 2; ++fr)
        a[fr] = *(const s16x8*)(ldsA + ((s * 4 + q) * 64 + wy * 32 + fr * 16 + l15) * 16);
      #pragma unroll
      for (int fc = 0; fc < 2; ++fc)
        b[fc] = *(const s16x8*)(ldsB + ((s * 4 + q) * 64 + wx * 32 + fc * 16 + l15) * 16);
      #pragma unroll
      for (int fr = 0; fr < 2; ++fr)
        #pragma unroll
        for (int fc = 0; fc < 2; ++fc)
          acc[fr][fc] = __builtin_amdgcn_mfma_f32_16x16x32_bf16(a[fr], b[fc], acc[fr][fc], 0, 0, 0);
    }
  }
  // epilogue: add bias, write zf fp32 and zb=[hi|lo] bf16
  #pragma unroll
  for (int fc = 0; fc < 2; ++fc) {
    int e = eb + wx * 32 + fc * 16 + l15;
    float bv = bias[e];
    #pragma unroll
    for (int fr = 0; fr < 2; ++fr)
      #pragma unroll
      for (int r = 0; r < 4; ++r) {
        int i = ib + wy * 32 + fr * 16 + q * 4 + r;
        float z = acc[fr][fc][r] + bv;
        zf[(size_t)i * 256 + e] = z;
        unsigned short hi = f2bf(z);
        zb[(size_t)i * 512 + e] = hi;
        zb[(size_t)i * 512 + 256 + e] = f2bf(z - bf2f(hi));
      }
  }
}

// GEMM2 + argmax epilogue. Logical K=768: A(zb) seg{0,1,2}->{hi,hi,lo}, B(cb2) seg{0,1,2}->{hi,lo,hi}
// score = G[i][j] - 0.5*ce[j]; candidates[jt][i] = packed u64 (enc(score)<<32 | (16383-j))
// BM=BN=128, 4 waves 2x2 (wave 64x64), grid (128 jt, 64 it)
__global__ __launch_bounds__(256, 2)
void k_gemm2(const unsigned short* __restrict__ zb, const unsigned short* __restrict__ cb2,
             const float* __restrict__ ce, unsigned long long* __restrict__ cand) {
  __shared__ __align__(16) uint8_t lds[2048 * 16];  // A 16KB @0, B 16KB @16384
  __shared__ unsigned long long csh[2][128];
  uint8_t* ldsA = lds;
  uint8_t* ldsB = lds + 1024 * 16;
  const int t = threadIdx.x, w = t >> 6, l = t & 63;
  const int wy = w >> 1, wx = w & 1, l15 = l & 15, q = l >> 4;
  const int ib = blockIdx.y * 128, jb = blockIdx.x * 128;
  f32x4 acc[4][4] = {};
  for (int kt = 0; kt < 12; ++kt) {
    int seg = kt >> 2, c0 = (kt & 3) * 64;
    int kA = (seg == 2 ? 256 : 0) + c0;
    int kB = (seg == 1 ? 256 : 0) + c0;
    __syncthreads();
    #pragma unroll
    for (int r = 0; r < 4; ++r) {
      int P = t + 256 * r;  // kp = P>>7, m = P&127; LDS layout [kp][m]
      gl2lds16(zb + (size_t)(ib + (P & 127)) * 512 + kA + (P >> 7) * 8, ldsA + P * 16);
    }
    #pragma unroll
    for (int r = 0; r < 4; ++r) {
      int P = t + 256 * r;
      gl2lds16(cb2 + (size_t)(jb + (P & 127)) * 512 + kB + (P >> 7) * 8, ldsB + P * 16);
    }
    __syncthreads();
    #pragma unroll
    for (int s = 0; s < 2; ++s) {
      s16x8 a[4], b[4];
      #pragma unroll
      for (int fr = 0; fr < 4; ++fr)
        a[fr] = *(const s16x8*)(ldsA + ((s * 4 + q) * 128 + wy * 64 + fr * 16 + l15) * 16);
      #pragma unroll
      for (int fc = 0; fc < 4; ++fc)
        b[fc] = *(const s16x8*)(ldsB + ((s * 4 + q) * 128 + wx * 64 + fc * 16 + l15) * 16);
      #pragma unroll
      for (int fr = 0; fr < 4; ++fr)
        #pragma unroll
        for (int fc = 0; fc < 4; ++fc)
          acc[fr][fc] = __builtin_amdgcn_mfma_f32_16x16x32_bf16(a[fr], b[fc], acc[fr][fc], 0, 0, 0);
    }
  }
  // epilogue: per-row argmax of score over this 128-col tile
  float cev[4];
  int jcol[4];
  #pragma unroll
  for (int fc = 0; fc < 4; ++fc) {
    jcol[fc] = jb + wx * 64 + fc * 16 + l15;
    cev[fc] = ce[jcol[fc]];
  }
  #pragma unroll
  for (int fr = 0; fr < 4; ++fr) {
    #pragma unroll
    for (int r = 0; r < 4; ++r) {
      unsigned long long best = 0ull;
      #pragma unroll
      for (int fc = 0; fc < 4; ++fc) {
        float sc = acc[fr][fc][r] - 0.5f * cev[fc];
        unsigned u = __float_as_uint(sc);
        u = (u & 0x80000000u) ? ~u : (u | 0x80000000u);  // monotone fp32 encoding
        unsigned long long p = (((unsigned long long)u) << 32) | (unsigned)(16383 - jcol[fc]);
        best = p > best ? p : best;
      }
      // reduce across the 16 lanes of this quad (they hold different cols, same rows)
      best = max(best, shfl_xor_u64(best, 1));
      best = max(best, shfl_xor_u64(best, 2));
      best = max(best, shfl_xor_u64(best, 4));
      best = max(best, shfl_xor_u64(best, 8));
      if (l15 == 0) csh[wx][wy * 64 + fr * 16 + q * 4 + r] = best;
    }
  }
  __syncthreads();
  if (t < 128) {
    unsigned long long a0 = csh[0][t], b0 = csh[1][t];
    cand[(size_t)blockIdx.x * 8192 + ib + t] = a0 > b0 ? a0 : b0;
  }
}

__global__ void k_argmin(const unsigned long long* __restrict__ cand, int* __restrict__ idx) {
  int i = blockIdx.x * 256 + threadIdx.x;
  unsigned long long best = 0ull;
  for (int jt = 0; jt < 128; ++jt) {
    unsigned long long v = cand[(size_t)jt * 8192 + i];
    best = v > best ? v : best;
  }
  idx[i] = 16383 - (int)(best & 0xFFFFu);
}

// loss partial: sum (codebook[idx[i]][e] - zf[i][e])^2, block-reduced, atomicAdd
__global__ void k_loss(const float* __restrict__ zf, const float* __restrict__ cbk,
                       const int* __restrict__ idx, float* __restrict__ lossw) {
  int t = threadIdx.x;
  size_t base = (size_t)blockIdx.x * 1024;
  float s = 0.0f;
  #pragma unroll
  for (int k = 0; k < 4; ++k) {
    size_t li = base + k * 256 + t;
    int i = (int)(li >> 8), e = (int)(li & 255);
    float d = cbk[(size_t)idx[i] * 256 + e] - zf[li];
    s += d * d;
  }
  #pragma unroll
  for (int m = 32; m; m >>= 1) s += __shfl_down(s, m, 64);
  __shared__ float ps[4];
  if ((t & 63) == 0) ps[t >> 6] = s;
  __syncthreads();
  if (t == 0) atomicAdd(lossw, ps[0] + ps[1] + ps[2] + ps[3]);
}

// out0[b][e][s] = codebook[idx[b*1024+s]][e]; block 0 thread 0 writes loss
__global__ void k_out(const float* __restrict__ cbk, const int* __restrict__ idx,
                      const float* __restrict__ lossw, float* __restrict__ out) {
  __shared__ int lidx[64];
  int blk = blockIdx.x;
  int b = blk >> 4, s0 = (blk & 15) * 64;
  int t = threadIdx.x;
  if (t < 64) lidx[t] = idx[b * 1024 + s0 + t];
  __syncthreads();
  int sl = t & 63, e0 = t >> 6;
  size_t ob = (size_t)b * 262144 + s0 + sl;
  size_t crow = (size_t)lidx[sl] * 256;
  for (int e = e0; e < 256; e += 4)
    out[ob + (size_t)e * 1024] = cbk[crow + e];
  if (blk == 0 && t == 0)
    out[2097152] = 1.25f * lossw[0] * (1.0f / 2097152.0f);
}

extern "C" void kernel_launch(void* const* d_in, const int* in_sizes, int n_in,
                              void* d_out, int out_size, void* d_ws, size_t ws_size,
                              hipStream_t stream) {
  const float* feats  = (const float*)d_in[0];
  const float* conv_w = (const float*)d_in[1];
  const float* conv_b = (const float*)d_in[2];
  const float* cbk    = (const float*)d_in[3];
  float* out = (float*)d_out;
  char* ws = (char*)d_ws;
  // workspace layout (bytes), ~73.1 MB total
  unsigned short* featsT = (unsigned short*)(ws);                  // 33,554,432
  unsigned short* W2     = (unsigned short*)(ws + 33554432);       //  1,048,576
  unsigned short* cb2    = (unsigned short*)(ws + 34603008);       // 16,777,216
  float*          ce     = (float*)(ws + 51380224);                //     65,536
  float*          zf     = (float*)(ws + 51445760);                //  8,388,608
  unsigned short* zb     = (unsigned short*)(ws + 59834368);       //  8,388,608
  unsigned long long* cand = (unsigned long long*)(ws + 68222976); //  8,388,608
  int*            idx    = (int*)(ws + 76611584);                  //     32,768
  float*          lossw  = (float*)(ws + 76644352);                //        256

  k_init<<<1, 64, 0, stream>>>(lossw);
  k_prep_cb<<<16384, 256, 0, stream>>>(cbk, cb2, ce);
  k_prep_w<<<256, 256, 0, stream>>>(conv_w, W2);
  k_tr_feats<<<dim3(32, 32, 8), 256, 0, stream>>>(feats, featsT);
  k_gemm1<<<dim3(4, 128), 256, 0, stream>>>(featsT, W2, conv_b, zf, zb);
  k_gemm2<<<dim3(128, 64), 256, 0, stream>>>(zb, cb2, ce, cand);
  k_argmin<<<32, 256, 0, stream>>>(cand, idx);
  k_loss<<<2048, 256, 0, stream>>>(zf, cbk, idx, lossw);
  k_out<<<128, 256, 0, stream>>>(cbk, idx, lossw, out);
}

// Round 2
// 317.433 us; speedup vs baseline: 1.7916x; 1.7916x over previous
//
#include <hip/hip_runtime.h>
#include <hip/hip_bf16.h>
#include <stdint.h>

// Problem constants
//   feats   [8,1024,32,32] fp32   -> rows i = b*1024 + (h*32+w), NI=8192
//   conv_w  [256,1024] fp32, conv_b [256] fp32, codebook [16384,256] fp32
// Outputs: z_q [8,256,32,32] fp32 (2097152) + loss scalar (1)
//
// Round-2 design:
//  - single bf16 precision (flips bounded at 1.22e-4 absmax; already passing)
//  - GEMM2 transposed (M=j codebook, N=i rows), K padded 256->320 with
//    col 256 = (-0.5*||e_j||^2  x  1.0) folding the bias term into MFMA
//  - epilogue: per-lane i32 packed (score<<14 | 16383-j) max, 2 shuffles

typedef float f32x4 __attribute__((ext_vector_type(4)));
typedef short s16x8 __attribute__((ext_vector_type(8)));

#define KP 320          // padded K for gemm2 operands
#define SCALE 4194304.0f  // 2^22

__device__ __forceinline__ void gl2lds16(const void* g, void* l) {
  __builtin_amdgcn_global_load_lds(
      (const __attribute__((address_space(1))) void*)g,
      (__attribute__((address_space(3))) void*)l, 16, 0, 0);
}

__device__ __forceinline__ unsigned short f2bf(float f) {
  unsigned u = __float_as_uint(f);
  u = u + 0x7FFFu + ((u >> 16) & 1u);
  return (unsigned short)(u >> 16);
}

// codebook fp32 [16384][256] -> cb2 bf16 [16384][320]: cols 0..255 = bf16(e),
// col 256 = bf16(-0.5*||e||^2), 257..319 = 0. Also writes zb pad cols for j<8192.
__global__ void k_prep_cb(const float* __restrict__ cbk,
                          unsigned short* __restrict__ cb2,
                          unsigned short* __restrict__ zb) {
  int j = blockIdx.x, t = threadIdx.x;
  float v = cbk[(size_t)j * 256 + t];
  cb2[(size_t)j * KP + t] = f2bf(v);
  float s = v * v;
  #pragma unroll
  for (int m = 32; m; m >>= 1) s += __shfl_down(s, m, 64);
  __shared__ float ps[4];
  if ((t & 63) == 0) ps[t >> 6] = s;
  __syncthreads();
  if (t == 0)
    cb2[(size_t)j * KP + 256] = f2bf(-0.5f * (ps[0] + ps[1] + ps[2] + ps[3]));
  if (t >= 1 && t < 64) cb2[(size_t)j * KP + 256 + t] = 0;
  if (j < 8192) {
    if (t == 0) zb[(size_t)j * KP + 256] = 0x3F80;  // 1.0 bf16
    if (t >= 1 && t < 64) zb[(size_t)j * KP + 256 + t] = 0;
  }
}

// conv_w [256][1024] -> W2 bf16 [256][1024]
__global__ void k_prep_w(const float* __restrict__ Wsrc, unsigned short* __restrict__ W2) {
  int e = blockIdx.x, t = threadIdx.x;
  #pragma unroll
  for (int k = 0; k < 4; ++k) {
    int c = t + k * 256;
    W2[(size_t)e * 1024 + c] = f2bf(Wsrc[(size_t)e * 1024 + c]);
  }
}

// feats [8][1024 c][1024 s] -> featsT bf16 [8192 i][1024 c], i=b*1024+s
__global__ void k_tr_feats(const float* __restrict__ feats, unsigned short* __restrict__ At) {
  __shared__ float tile[32][33];
  int b = blockIdx.z, c0 = blockIdx.x * 32, s0 = blockIdx.y * 32;
  int t = threadIdx.x;
  int tc = t >> 5, ts = t & 31;
  #pragma unroll
  for (int k = 0; k < 4; ++k)
    tile[tc + k * 8][ts] = feats[((size_t)b * 1024 + c0 + tc + k * 8) * 1024 + s0 + ts];
  __syncthreads();
  #pragma unroll
  for (int k = 0; k < 4; ++k) {
    int sr = tc + k * 8, cw = ts;
    At[(size_t)(b * 1024 + s0 + sr) * 1024 + c0 + cw] = f2bf(tile[cw][sr]);
  }
}

// GEMM1: zf[i][e] = sum_c feats[i][c]*W[e][c] + b[e]   (K=1024, bf16)
// BM=BN=64, 4 waves 2x2 (wave 32x32), grid (4,128)
__global__ __launch_bounds__(256, 2)
void k_gemm1(const unsigned short* __restrict__ At, const unsigned short* __restrict__ Bw,
             const float* __restrict__ bias, float* __restrict__ zf,
             unsigned short* __restrict__ zb) {
  __shared__ __align__(16) uint8_t lds[1024 * 16];  // A 8KB @0, B 8KB @8192
  uint8_t* ldsA = lds;
  uint8_t* ldsB = lds + 512 * 16;
  const int t = threadIdx.x, w = t >> 6, l = t & 63;
  const int wy = w >> 1, wx = w & 1, l15 = l & 15, q = l >> 4;
  const int ib = blockIdx.y * 64, eb = blockIdx.x * 64;
  f32x4 acc[2][2] = {};
  for (int kt = 0; kt < 16; ++kt) {
    int c0 = kt * 64;
    __syncthreads();
    #pragma unroll
    for (int r = 0; r < 2; ++r) {
      int P = t + 256 * r;  // packet: kp = P>>6, m = P&63; LDS layout [kp][m]
      gl2lds16(At + (size_t)(ib + (P & 63)) * 1024 + c0 + (P >> 6) * 8, ldsA + P * 16);
    }
    #pragma unroll
    for (int r = 0; r < 2; ++r) {
      int P = t + 256 * r;
      gl2lds16(Bw + (size_t)(eb + (P & 63)) * 1024 + c0 + (P >> 6) * 8, ldsB + P * 16);
    }
    __syncthreads();
    #pragma unroll
    for (int s = 0; s < 2; ++s) {
      s16x8 a[2], b[2];
      #pragma unroll
      for (int fr = 0; fr < 2; ++fr)
        a[fr] = *(const s16x8*)(ldsA + ((s * 4 + q) * 64 + wy * 32 + fr * 16 + l15) * 16);
      #pragma unroll
      for (int fc = 0; fc < 2; ++fc)
        b[fc] = *(const s16x8*)(ldsB + ((s * 4 + q) * 64 + wx * 32 + fc * 16 + l15) * 16);
      #pragma unroll
      for (int fr = 0; fr < 2; ++fr)
        #pragma unroll
        for (int fc = 0; fc < 2; ++fc)
          acc[fr][fc] = __builtin_amdgcn_mfma_f32_16x16x32_bf16(a[fr], b[fc], acc[fr][fc], 0, 0, 0);
    }
  }
  #pragma unroll
  for (int fc = 0; fc < 2; ++fc) {
    int e = eb + wx * 32 + fc * 16 + l15;
    float bv = bias[e];
    #pragma unroll
    for (int fr = 0; fr < 2; ++fr)
      #pragma unroll
      for (int r = 0; r < 4; ++r) {
        int i = ib + wy * 32 + fr * 16 + q * 4 + r;
        float z = acc[fr][fc][r] + bv;
        zf[(size_t)i * 256 + e] = z;
        zb[(size_t)i * KP + e] = f2bf(z);
      }
  }
}

// GEMM2 transposed + argmax epilogue.
// A = cb2 [16384 j][320], B = zb [8192 i][320]. score[j][i] accumulates
// z_i.e_j - 0.5||e_j||^2 via the folded col 256. BM=128(j) BN=128(i),
// 4 waves 2x2 (wave 64x64), grid (128 jb, 64 ib).
// cand[jblk][i] = packed i32 (cvt(score*2^22)<<14)|(16383-j), i32-max partial.
__global__ __launch_bounds__(256, 2)
void k_gemm2(const unsigned short* __restrict__ cb2, const unsigned short* __restrict__ zb,
             int* __restrict__ cand) {
  __shared__ __align__(16) uint8_t lds[2048 * 16];  // A 16KB @0, B 16KB @16384
  __shared__ int csh[2][128];
  uint8_t* ldsA = lds;
  uint8_t* ldsB = lds + 1024 * 16;
  const int t = threadIdx.x, w = t >> 6, l = t & 63;
  const int wy = w >> 1, wx = w & 1, l15 = l & 15, q = l >> 4;
  const int jb = blockIdx.x * 128, ib = blockIdx.y * 128;
  f32x4 acc[4][4] = {};
  for (int kt = 0; kt < 5; ++kt) {
    int c0 = kt * 64;
    __syncthreads();
    #pragma unroll
    for (int r = 0; r < 4; ++r) {
      int P = t + 256 * r;  // kp = P>>7, m = P&127; LDS layout [kp][m]
      gl2lds16(cb2 + (size_t)(jb + (P & 127)) * KP + c0 + (P >> 7) * 8, ldsA + P * 16);
    }
    #pragma unroll
    for (int r = 0; r < 4; ++r) {
      int P = t + 256 * r;
      gl2lds16(zb + (size_t)(ib + (P & 127)) * KP + c0 + (P >> 7) * 8, ldsB + P * 16);
    }
    __syncthreads();
    #pragma unroll
    for (int s = 0; s < 2; ++s) {
      s16x8 a[4], b[4];
      #pragma unroll
      for (int fr = 0; fr < 4; ++fr)
        a[fr] = *(const s16x8*)(ldsA + ((s * 4 + q) * 128 + wy * 64 + fr * 16 + l15) * 16);
      #pragma unroll
      for (int fc = 0; fc < 4; ++fc)
        b[fc] = *(const s16x8*)(ldsB + ((s * 4 + q) * 128 + wx * 64 + fc * 16 + l15) * 16);
      #pragma unroll
      for (int fr = 0; fr < 4; ++fr)
        #pragma unroll
        for (int fc = 0; fc < 4; ++fc)
          acc[fr][fc] = __builtin_amdgcn_mfma_f32_16x16x32_bf16(a[fr], b[fc], acc[fr][fc], 0, 0, 0);
    }
  }
  // epilogue: per-i argmax over this block's 128 j values.
  // j = jb + wy*64 + fr*16 + q*4 + r  (on q/r/fr), i = ib + wx*64 + fc*16 + l15
  const int encq = 16383 - (jb + wy * 64 + q * 4);  // enc = encq - fr*16 - r
  #pragma unroll
  for (int fc = 0; fc < 4; ++fc) {
    int best = 0x80000000;
    #pragma unroll
    for (int fr = 0; fr < 4; ++fr)
      #pragma unroll
      for (int r = 0; r < 4; ++r) {
        int si = (int)(acc[fr][fc][r] * SCALE);   // |score|*2^22 < 2^17
        int p = (int)(((unsigned)si << 14) | (unsigned)(encq - fr * 16 - r));
        best = p > best ? p : best;
      }
    best = max(best, __shfl_xor(best, 16, 64));   // reduce over q (j groups)
    best = max(best, __shfl_xor(best, 32, 64));
    if (l < 16) csh[wy][wx * 64 + fc * 16 + l15] = best;
  }
  __syncthreads();
  if (t < 128) {
    int a0 = csh[0][t], b0 = csh[1][t];
    cand[(size_t)blockIdx.x * 8192 + ib + t] = a0 > b0 ? a0 : b0;
  }
}

__global__ void k_argmin(const int* __restrict__ cand, int* __restrict__ idx,
                         float* __restrict__ lossw) {
  int i = blockIdx.x * 256 + threadIdx.x;
  int best = 0x80000000;
  for (int jt = 0; jt < 128; ++jt) {
    int v = cand[(size_t)jt * 8192 + i];
    best = v > best ? v : best;
  }
  idx[i] = 16383 - (best & 0x3FFF);
  if (i == 0) lossw[0] = 0.0f;
}

// loss partial: sum (codebook[idx[i]][e] - zf[i][e])^2
__global__ void k_loss(const float* __restrict__ zf, const float* __restrict__ cbk,
                       const int* __restrict__ idx, float* __restrict__ lossw) {
  int t = threadIdx.x;
  size_t base = (size_t)blockIdx.x * 1024;
  float s = 0.0f;
  #pragma unroll
  for (int k = 0; k < 4; ++k) {
    size_t li = base + k * 256 + t;
    int i = (int)(li >> 8), e = (int)(li & 255);
    float d = cbk[(size_t)idx[i] * 256 + e] - zf[li];
    s += d * d;
  }
  #pragma unroll
  for (int m = 32; m; m >>= 1) s += __shfl_down(s, m, 64);
  __shared__ float ps[4];
  if ((t & 63) == 0) ps[t >> 6] = s;
  __syncthreads();
  if (t == 0) atomicAdd(lossw, ps[0] + ps[1] + ps[2] + ps[3]);
}

// out0[b][e][s] = codebook[idx[b*1024+s]][e]; block 0 thread 0 writes loss
__global__ void k_out(const float* __restrict__ cbk, const int* __restrict__ idx,
                      const float* __restrict__ lossw, float* __restrict__ out) {
  __shared__ int lidx[64];
  int blk = blockIdx.x;
  int b = blk >> 4, s0 = (blk & 15) * 64;
  int t = threadIdx.x;
  if (t < 64) lidx[t] = idx[b * 1024 + s0 + t];
  __syncthreads();
  int sl = t & 63, e0 = t >> 6;
  size_t ob = (size_t)b * 262144 + s0 + sl;
  size_t crow = (size_t)lidx[sl] * 256;
  for (int e = e0; e < 256; e += 4)
    out[ob + (size_t)e * 1024] = cbk[crow + e];
  if (blk == 0 && t == 0)
    out[2097152] = 1.25f * lossw[0] * (1.0f / 2097152.0f);
}

extern "C" void kernel_launch(void* const* d_in, const int* in_sizes, int n_in,
                              void* d_out, int out_size, void* d_ws, size_t ws_size,
                              hipStream_t stream) {
  const float* feats  = (const float*)d_in[0];
  const float* conv_w = (const float*)d_in[1];
  const float* conv_b = (const float*)d_in[2];
  const float* cbk    = (const float*)d_in[3];
  float* out = (float*)d_out;
  char* ws = (char*)d_ws;
  // workspace layout (bytes), ~45.6 MB total
  unsigned short* featsT = (unsigned short*)(ws);                  // 16,777,216
  unsigned short* W2     = (unsigned short*)(ws + 16777216);       //    524,288
  unsigned short* cb2    = (unsigned short*)(ws + 17301504);       // 10,485,760
  float*          zf     = (float*)(ws + 27787264);                //  8,388,608
  unsigned short* zb     = (unsigned short*)(ws + 36175872);       //  5,242,880
  int*            cand   = (int*)(ws + 41418752);                  //  4,194,304
  int*            idx    = (int*)(ws + 45613056);                  //     32,768
  float*          lossw  = (float*)(ws + 45645824);                //        256

  k_prep_cb<<<16384, 256, 0, stream>>>(cbk, cb2, zb);
  k_prep_w<<<256, 256, 0, stream>>>(conv_w, W2);
  k_tr_feats<<<dim3(32, 32, 8), 256, 0, stream>>>(feats, featsT);
  k_gemm1<<<dim3(4, 128), 256, 0, stream>>>(featsT, W2, conv_b, zf, zb);
  k_gemm2<<<dim3(128, 64), 256, 0, stream>>>(cb2, zb, cand);
  k_argmin<<<32, 256, 0, stream>>>(cand, idx, lossw);
  k_loss<<<2048, 256, 0, stream>>>(zf, cbk, idx, lossw);
  k_out<<<128, 256, 0, stream>>>(cbk, idx, lossw, out);
}

// Round 3
// 295.297 us; speedup vs baseline: 1.9260x; 1.0750x over previous
//
#include <hip/hip_runtime.h>
#include <hip/hip_bf16.h>
#include <stdint.h>

// Problem: feats[8,1024,32,32]f32, conv_w[256,1024]f32, conv_b[256]f32,
// codebook[16384,256]f32 -> z_q[8,256,32,32]f32 (2097152) + loss scalar.
//
// Round-3 design:
//  - gemm2: BM=256(j) x BN=128(i), 512 thr / 8 waves, grid(64,64)
//  - loss computed from packed best score: dist_i = ||z_i||^2 - 2*score_i
//    (score = z.e - 0.5||e||^2 via folded K-column) -> no zf buffer, no loss pass
//  - 4 launches: k_prep (all preps fused), k_gemm1, k_gemm2, k_final

typedef float f32x4 __attribute__((ext_vector_type(4)));
typedef short s16x8 __attribute__((ext_vector_type(8)));

#define KP 320            // padded K for gemm2 operands
#define SCALE 4194304.0f  // 2^22

__device__ __forceinline__ void gl2lds16(const void* g, void* l) {
  __builtin_amdgcn_global_load_lds(
      (const __attribute__((address_space(1))) void*)g,
      (__attribute__((address_space(3))) void*)l, 16, 0, 0);
}

__device__ __forceinline__ unsigned short f2bf(float f) {
  unsigned u = __float_as_uint(f);
  u = u + 0x7FFFu + ((u >> 16) & 1u);
  return (unsigned short)(u >> 16);
}
__device__ __forceinline__ float bf2f(unsigned short u) {
  return __uint_as_float(((unsigned)u) << 16);
}

// Fused prep. Blocks [0,16384): codebook -> cb2 bf16 [16384][320] with
// col256 = -0.5||e||^2, pad 0; zb pad cols for rows<8192. [16384,16640):
// conv_w -> W2 bf16. [16640,24832): feats transpose -> featsT bf16 [8192][1024].
// Block 0 also zero-inits lossw (float accum + int counter).
__global__ void k_prep(const float* __restrict__ cbk, const float* __restrict__ Wsrc,
                       const float* __restrict__ feats,
                       unsigned short* __restrict__ cb2, unsigned short* __restrict__ W2,
                       unsigned short* __restrict__ At, unsigned short* __restrict__ zb,
                       float* __restrict__ lossw) {
  __shared__ float tile[32][33];
  __shared__ float ps[4];
  int blk = blockIdx.x, t = threadIdx.x;
  if (blk == 0 && t < 2) ((int*)lossw)[t] = 0;
  if (blk < 16384) {
    int j = blk;
    float v = cbk[(size_t)j * 256 + t];
    cb2[(size_t)j * KP + t] = f2bf(v);
    float s = v * v;
    #pragma unroll
    for (int m = 32; m; m >>= 1) s += __shfl_down(s, m, 64);
    if ((t & 63) == 0) ps[t >> 6] = s;
    __syncthreads();
    if (t == 0) cb2[(size_t)j * KP + 256] = f2bf(-0.5f * (ps[0] + ps[1] + ps[2] + ps[3]));
    if (t >= 1 && t < 64) cb2[(size_t)j * KP + 256 + t] = 0;
    if (j < 8192) {
      if (t == 0) zb[(size_t)j * KP + 256] = 0x3F80;  // 1.0 bf16
      if (t >= 1 && t < 64) zb[(size_t)j * KP + 256 + t] = 0;
    }
  } else if (blk < 16640) {
    int e = blk - 16384;
    #pragma unroll
    for (int k = 0; k < 4; ++k) {
      int c = t + k * 256;
      W2[(size_t)e * 1024 + c] = f2bf(Wsrc[(size_t)e * 1024 + c]);
    }
  } else {
    int id = blk - 16640;
    int b = id >> 10, c0 = ((id >> 5) & 31) * 32, s0 = (id & 31) * 32;
    int tc = t >> 5, ts = t & 31;
    #pragma unroll
    for (int k = 0; k < 4; ++k)
      tile[tc + k * 8][ts] = feats[((size_t)b * 1024 + c0 + tc + k * 8) * 1024 + s0 + ts];
    __syncthreads();
    #pragma unroll
    for (int k = 0; k < 4; ++k) {
      int sr = tc + k * 8, cw = ts;
      At[(size_t)(b * 1024 + s0 + sr) * 1024 + c0 + cw] = f2bf(tile[cw][sr]);
    }
  }
}

// GEMM1: z[i][e] = sum_c feats[i][c]*W[e][c] + b[e] (K=1024 bf16), writes zb only.
// BM=BN=64, 4 waves 2x2 (wave 32x32), grid (4,128)
__global__ __launch_bounds__(256, 2)
void k_gemm1(const unsigned short* __restrict__ At, const unsigned short* __restrict__ Bw,
             const float* __restrict__ bias, unsigned short* __restrict__ zb) {
  __shared__ __align__(16) uint8_t lds[1024 * 16];
  uint8_t* ldsA = lds;
  uint8_t* ldsB = lds + 512 * 16;
  const int t = threadIdx.x, w = t >> 6, l = t & 63;
  const int wy = w >> 1, wx = w & 1, l15 = l & 15, q = l >> 4;
  const int ib = blockIdx.y * 64, eb = blockIdx.x * 64;
  f32x4 acc[2][2] = {};
  for (int kt = 0; kt < 16; ++kt) {
    int c0 = kt * 64;
    __syncthreads();
    #pragma unroll
    for (int r = 0; r < 2; ++r) {
      int P = t + 256 * r;  // kp = P>>6, m = P&63; LDS layout [kp][m]
      gl2lds16(At + (size_t)(ib + (P & 63)) * 1024 + c0 + (P >> 6) * 8, ldsA + P * 16);
    }
    #pragma unroll
    for (int r = 0; r < 2; ++r) {
      int P = t + 256 * r;
      gl2lds16(Bw + (size_t)(eb + (P & 63)) * 1024 + c0 + (P >> 6) * 8, ldsB + P * 16);
    }
    __syncthreads();
    #pragma unroll
    for (int s = 0; s < 2; ++s) {
      s16x8 a[2], b[2];
      #pragma unroll
      for (int fr = 0; fr < 2; ++fr)
        a[fr] = *(const s16x8*)(ldsA + ((s * 4 + q) * 64 + wy * 32 + fr * 16 + l15) * 16);
      #pragma unroll
      for (int fc = 0; fc < 2; ++fc)
        b[fc] = *(const s16x8*)(ldsB + ((s * 4 + q) * 64 + wx * 32 + fc * 16 + l15) * 16);
      #pragma unroll
      for (int fr = 0; fr < 2; ++fr)
        #pragma unroll
        for (int fc = 0; fc < 2; ++fc)
          acc[fr][fc] = __builtin_amdgcn_mfma_f32_16x16x32_bf16(a[fr], b[fc], acc[fr][fc], 0, 0, 0);
    }
  }
  #pragma unroll
  for (int fc = 0; fc < 2; ++fc) {
    int e = eb + wx * 32 + fc * 16 + l15;
    float bv = bias[e];
    #pragma unroll
    for (int fr = 0; fr < 2; ++fr)
      #pragma unroll
      for (int r = 0; r < 4; ++r) {
        int i = ib + wy * 32 + fr * 16 + q * 4 + r;
        zb[(size_t)i * KP + e] = f2bf(acc[fr][fc][r] + bv);
      }
  }
}

// GEMM2 + argmax. A = cb2 [16384 j][320], B = zb [8192 i][320].
// BM=256(j) BN=128(i), 512 thr, 8 waves 4(wy) x 2(wx), wave 64x64.
// grid (64 jb, 64 ib). cand[jblk][i] = packed (cvt(score*2^22)<<14)|(16383-j).
__global__ __launch_bounds__(512, 4)
void k_gemm2(const unsigned short* __restrict__ cb2, const unsigned short* __restrict__ zb,
             int* __restrict__ cand) {
  __shared__ __align__(16) uint8_t lds[3072 * 16];  // A 32KB @0, B 16KB @32768
  __shared__ int csh[4][128];
  uint8_t* ldsA = lds;
  uint8_t* ldsB = lds + 2048 * 16;
  const int t = threadIdx.x, w = t >> 6, l = t & 63;
  const int wy = w >> 1, wx = w & 1, l15 = l & 15, q = l >> 4;
  const int jb = blockIdx.x * 256, ib = blockIdx.y * 128;
  f32x4 acc[4][4] = {};
  for (int kt = 0; kt < 5; ++kt) {
    int c0 = kt * 64;
    __syncthreads();
    #pragma unroll
    for (int r = 0; r < 4; ++r) {
      int P = t + 512 * r;  // A: 2048 packets, m = P&255, kp = P>>8
      gl2lds16(cb2 + (size_t)(jb + (P & 255)) * KP + c0 + (P >> 8) * 8, ldsA + P * 16);
    }
    #pragma unroll
    for (int r = 0; r < 2; ++r) {
      int P = t + 512 * r;  // B: 1024 packets, m = P&127, kp = P>>7
      gl2lds16(zb + (size_t)(ib + (P & 127)) * KP + c0 + (P >> 7) * 8, ldsB + P * 16);
    }
    __syncthreads();
    #pragma unroll
    for (int s = 0; s < 2; ++s) {
      s16x8 a[4], b[4];
      #pragma unroll
      for (int fr = 0; fr < 4; ++fr)
        a[fr] = *(const s16x8*)(ldsA + ((s * 4 + q) * 256 + wy * 64 + fr * 16 + l15) * 16);
      #pragma unroll
      for (int fc = 0; fc < 4; ++fc)
        b[fc] = *(const s16x8*)(ldsB + ((s * 4 + q) * 128 + wx * 64 + fc * 16 + l15) * 16);
      #pragma unroll
      for (int fr = 0; fr < 4; ++fr)
        #pragma unroll
        for (int fc = 0; fc < 4; ++fc)
          acc[fr][fc] = __builtin_amdgcn_mfma_f32_16x16x32_bf16(a[fr], b[fc], acc[fr][fc], 0, 0, 0);
    }
  }
  // j = jb + wy*64 + fr*16 + q*4 + r ; i = ib + wx*64 + fc*16 + l15
  const int encq = 16383 - (jb + wy * 64 + q * 4);
  #pragma unroll
  for (int fc = 0; fc < 4; ++fc) {
    int best = (int)0x80000000;
    #pragma unroll
    for (int fr = 0; fr < 4; ++fr)
      #pragma unroll
      for (int r = 0; r < 4; ++r) {
        int si = (int)(acc[fr][fc][r] * SCALE);  // |score|*2^22 < 2^17
        int p = (int)(((unsigned)si << 14) | (unsigned)(encq - fr * 16 - r));
        best = p > best ? p : best;
      }
    best = max(best, __shfl_xor(best, 16, 64));  // reduce over q
    best = max(best, __shfl_xor(best, 32, 64));
    if (l < 16) csh[wy][wx * 64 + fc * 16 + l] = best;
  }
  __syncthreads();
  if (t < 128) {
    int m0 = max(max(csh[0][t], csh[1][t]), max(csh[2][t], csh[3][t]));
    cand[(size_t)blockIdx.x * 8192 + ib + t] = m0;
  }
}

// Fused argmin + loss + output gather. 128 blocks x 256 thr; block = (b, s0)
// covering 64 rows. dist_i = ||z_i||^2 - 2*score_i (bf16-consistent).
__global__ void k_final(const unsigned short* __restrict__ zb, const int* __restrict__ cand,
                        const float* __restrict__ cbk, float* __restrict__ lossw,
                        float* __restrict__ out) {
  __shared__ int lidx[64];
  __shared__ float ps[4];
  int blk = blockIdx.x, t = threadIdx.x;
  int b = blk >> 4, s0 = (blk & 15) * 64;
  int row = t >> 2, c = t & 3;
  int gi = b * 1024 + s0 + row;
  // ||z||^2 partial over 64 bf16 elems
  const unsigned short* zrow = zb + (size_t)gi * KP + c * 64;
  float ss = 0.0f;
  #pragma unroll
  for (int k = 0; k < 64; k += 4) {
    ushort4 v = *(const ushort4*)(zrow + k);
    float a0 = bf2f(v.x), a1 = bf2f(v.y), a2 = bf2f(v.z), a3 = bf2f(v.w);
    ss += a0 * a0 + a1 * a1 + a2 * a2 + a3 * a3;
  }
  // argmax partial over 64 jt blocks
  int best = (int)0x80000000;
  #pragma unroll 4
  for (int k = 0; k < 16; ++k) {
    int v = cand[(size_t)(c + 4 * k) * 8192 + gi];
    best = v > best ? v : best;
  }
  best = max(best, __shfl_xor(best, 1, 64));
  best = max(best, __shfl_xor(best, 2, 64));
  ss += __shfl_xor(ss, 1, 64);
  ss += __shfl_xor(ss, 2, 64);
  float dist = 0.0f;
  if (c == 0) {
    lidx[row] = 16383 - (best & 0x3FFF);
    dist = ss - 2.0f * (float)(best >> 14) * (1.0f / SCALE);
  }
  float v = dist;
  #pragma unroll
  for (int m = 32; m; m >>= 1) v += __shfl_down(v, m, 64);
  if ((t & 63) == 0) ps[t >> 6] = v;
  __syncthreads();
  if (t == 0) {
    float part = ps[0] + ps[1] + ps[2] + ps[3];
    atomicAdd(lossw, part);
    __threadfence();
    int cnt = atomicAdd((int*)lossw + 1, 1);
    if (cnt == 127) {
      __threadfence();
      float total = atomicAdd(lossw, 0.0f);
      out[2097152] = 1.25f * total * (1.0f / 2097152.0f);
    }
  }
  // gather z_q: out[b][e][s0+sl] = cbk[lidx[sl]][e]
  int sl = t & 63, e0 = t >> 6;
  size_t ob = (size_t)b * 262144 + s0 + sl;
  size_t crow = (size_t)lidx[sl] * 256;
  for (int e = e0; e < 256; e += 4)
    out[ob + (size_t)e * 1024] = cbk[crow + e];
}

extern "C" void kernel_launch(void* const* d_in, const int* in_sizes, int n_in,
                              void* d_out, int out_size, void* d_ws, size_t ws_size,
                              hipStream_t stream) {
  const float* feats  = (const float*)d_in[0];
  const float* conv_w = (const float*)d_in[1];
  const float* conv_b = (const float*)d_in[2];
  const float* cbk    = (const float*)d_in[3];
  float* out = (float*)d_out;
  char* ws = (char*)d_ws;
  // workspace layout (bytes), ~35.2 MB total
  unsigned short* featsT = (unsigned short*)(ws);                  // 16,777,216
  unsigned short* W2     = (unsigned short*)(ws + 16777216);       //    524,288
  unsigned short* cb2    = (unsigned short*)(ws + 17301504);       // 10,485,760
  unsigned short* zb     = (unsigned short*)(ws + 27787264);       //  5,242,880
  int*            cand   = (int*)(ws + 33030144);                  //  2,097,152
  float*          lossw  = (float*)(ws + 35127296);                //        256

  k_prep<<<24832, 256, 0, stream>>>(cbk, conv_w, feats, cb2, W2, featsT, zb, lossw);
  k_gemm1<<<dim3(4, 128), 256, 0, stream>>>(featsT, W2, conv_b, zb);
  k_gemm2<<<dim3(64, 64), 512, 0, stream>>>(cb2, zb, cand);
  k_final<<<128, 256, 0, stream>>>(zb, cand, cbk, lossw, out);
}